// Round 1
// 124.658 us; speedup vs baseline: 1.1095x; 1.1095x over previous
//
#include <hip/hip_runtime.h>
#include <hip/hip_bf16.h>

#define DD 32
#define P_MAX 118
#define N_MAX 236
#define TBL (P_MAX * N_MAX)

// native clang vector types for nontemporal builtins (HIP_vector_type invalid)
typedef int   ivec4 __attribute__((ext_vector_type(4)));
typedef float fvec4 __attribute__((ext_vector_type(4)));

// ws float offsets (states now live in LDS, not ws)
#define UOF 0                        // U_T 32x118
#define VOF (DD * P_MAX)             // V_T 32x236 at 3776
#define MOF (VOF + DD * N_MAX)       // M2[2][32] + S[2] + c2[2] at 11328
#define TOF (MOF + 68)               // table (float2) at 11396 floats

// ---------------------------------------------------------------------------
// Kernel 1: fused chain + UV projection + epilogue fold.
// grid = 2 blocks x 256. Wave 0 runs the serial SiLU-matvec chain with
// readlane broadcast (critical path unchanged), states staged in LDS.
// Then all 4 waves project states through W1 (lane j fixed -> W1 row in
// registers; state reads are broadcast ds_read_b128, conflict-free).
// Block 0 additionally precomputes M2 = (Wr@W2) * ln_g (2x32), S = rowsum,
// c2 = (Wr@W2)@ln_b + Wr@b2 + br  -- the whole post-LN epilogue folded.
// ---------------------------------------------------------------------------
__global__ __launch_bounds__(256) void chain_uv_kernel(
    const float* __restrict__ emb,
    const float* __restrict__ Wp, const float* __restrict__ bp,
    const float* __restrict__ Wn, const float* __restrict__ bn,
    const float* __restrict__ W1, const float* __restrict__ b1,
    const float* __restrict__ ln_g, const float* __restrict__ ln_b,
    const float* __restrict__ W2, const float* __restrict__ b2,
    const float* __restrict__ Wr, const float* __restrict__ br,
    float* __restrict__ ws)
{
    __shared__ __align__(16) float st[N_MAX * DD];   // 30.2 KB states
    __shared__ float m2s[64];
    __shared__ float mraw[64];

    const int tid = threadIdx.x;
    const bool prot = (blockIdx.x == 0);
    const int len = prot ? P_MAX : N_MAX;

    // ---- phase 1: serial chain (wave 0 only) ----
    if (tid < 64) {
        const int ch = tid & 31;
        const float* W = prot ? Wp : Wn;
        const float* bb = prot ? bp : bn;

        float w[32];
#pragma unroll
        for (int q = 0; q < 8; ++q) {
            float4 v = reinterpret_cast<const float4*>(W + ch * 32)[q];
            w[4 * q + 0] = v.x; w[4 * q + 1] = v.y;
            w[4 * q + 2] = v.z; w[4 * q + 3] = v.w;
        }
        const float bias = bb[ch];
        float p = (prot ? emb : emb + DD)[ch];

        for (int t = 0; t < len; ++t) {
            float e = __expf(-p);
            float s = p * __builtin_amdgcn_rcpf(1.0f + e);
            int sb = __float_as_int(s);

            float a0 = bias, a1 = 0.0f, a2 = 0.0f, a3 = 0.0f;
#pragma unroll
            for (int k = 0; k < 32; k += 4) {
                a0 += __int_as_float(__builtin_amdgcn_readlane(sb, k + 0)) * w[k + 0];
                a1 += __int_as_float(__builtin_amdgcn_readlane(sb, k + 1)) * w[k + 1];
                a2 += __int_as_float(__builtin_amdgcn_readlane(sb, k + 2)) * w[k + 2];
                a3 += __int_as_float(__builtin_amdgcn_readlane(sb, k + 3)) * w[k + 3];
            }
            p = (a0 + a1) + (a2 + a3);
            // both halves hold identical p; same-address 2-way LDS write is free
            st[t * DD + ch] = p;
        }
    }
    __syncthreads();

    // ---- phase 2: UV projection (all 256 threads) ----
    {
        const int j = tid & 31;      // output channel, fixed per lane
        const int t0 = tid >> 5;     // 0..7
        const float* w1row = W1 + j * 64 + (prot ? 0 : 32);
        float wr[32];
#pragma unroll
        for (int q = 0; q < 8; ++q) {
            float4 v = reinterpret_cast<const float4*>(w1row)[q];
            wr[4 * q + 0] = v.x; wr[4 * q + 1] = v.y;
            wr[4 * q + 2] = v.z; wr[4 * q + 3] = v.w;
        }
        const float base = prot ? 0.0f : b1[j];
        float* op = ws + (prot ? UOF : VOF) + j * len;

        for (int t = t0; t < len; t += 8) {
            const float* sp = st + t * DD;
            float acc = base;
#pragma unroll
            for (int q = 0; q < 8; ++q) {
                float4 s4 = *reinterpret_cast<const float4*>(sp + 4 * q);
                acc = fmaf(s4.x, wr[4 * q + 0], acc);
                acc = fmaf(s4.y, wr[4 * q + 1], acc);
                acc = fmaf(s4.z, wr[4 * q + 2], acc);
                acc = fmaf(s4.w, wr[4 * q + 3], acc);
            }
            op[t] = acc;
        }
    }

    // ---- phase 3 (block 0 only): fold LN/W2/Wr epilogue into M2,S,c2 ----
    if (prot) {
        if (tid < 64) {
            const int r = tid >> 5;      // 0..1
            const int k = tid & 31;
            float acc = 0.0f;
#pragma unroll
            for (int jj = 0; jj < 32; ++jj)
                acc = fmaf(Wr[r * 32 + jj], W2[jj * 32 + k], acc);
            mraw[tid] = acc;                 // raw (Wr@W2)[r][k]
            const float m2 = acc * ln_g[k];
            m2s[tid] = m2;
            ws[MOF + tid] = m2;              // M2
        }
        __syncthreads();
        if (tid < 2) {
            const int r = tid;
            float S = 0.0f, cb = 0.0f;
#pragma unroll
            for (int k = 0; k < 32; ++k) {
                S += m2s[r * 32 + k];
                cb = fmaf(mraw[r * 32 + k], ln_b[k], cb);
            }
            float c = br[r] + cb;
#pragma unroll
            for (int jj = 0; jj < 32; ++jj)
                c = fmaf(Wr[r * 32 + jj], b2[jj], c);
            ws[MOF + 64 + r] = S;
            ws[MOF + 66 + r] = c;
        }
    }
}

// ---------------------------------------------------------------------------
// Kernel 2: build the table with the folded epilogue.
//   h = silu(U_T[:,pi] + V_T[:,ni]);  mu, var;  out = inv*(M2 h - mu S) + c2
// ~400 VALU ops/thread vs ~1500 before (the 1024-fma W2 matvec is gone).
// ---------------------------------------------------------------------------
__global__ __launch_bounds__(64, 1) void table_kernel(
    const float* __restrict__ ws,
    float2* __restrict__ table)
{
    const int e = blockIdx.x * 64 + threadIdx.x;
    if (e >= TBL) return;
    const int pi = e / N_MAX;
    const int ni = e - pi * N_MAX;

    const float* UT = ws + UOF;   // 32 x 118
    const float* VT = ws + VOF;   // 32 x 236
    const float* M2 = ws + MOF;   // 2x32 + S[2] + c2[2]

    float h[32];
    float mu = 0.0f;
#pragma unroll
    for (int j = 0; j < 32; ++j) {
        float a = UT[j * P_MAX + pi] + VT[j * N_MAX + ni];
        float ee = __expf(-a);
        float s = a * __builtin_amdgcn_rcpf(1.0f + ee);
        h[j] = s;
        mu += s;
    }
    mu *= (1.0f / 32.0f);
    float var = 0.0f;
#pragma unroll
    for (int j = 0; j < 32; ++j) {
        float d = h[j] - mu;
        var = fmaf(d, d, var);
    }
    var *= (1.0f / 32.0f);
    const float inv = __builtin_amdgcn_rsqf(var + 1e-5f);

    float d0 = 0.0f, d1 = 0.0f;
#pragma unroll
    for (int k = 0; k < 32; ++k) {
        d0 = fmaf(M2[k],      h[k], d0);
        d1 = fmaf(M2[32 + k], h[k], d1);
    }
    const float S0 = M2[64], S1 = M2[65];
    const float c0 = M2[66], c1 = M2[67];
    table[e] = make_float2(inv * (d0 - mu * S0) + c0,
                           inv * (d1 - mu * S1) + c1);
}

// ---------------------------------------------------------------------------
// Kernel 3: gather, 4 samples/thread. Nontemporal on the x-stream and the
// out-stream (read/write-once, 8 MB each) so the L2 stays dedicated to the
// 223 KB table.
// ---------------------------------------------------------------------------
__global__ __launch_bounds__(256) void gather_kernel(
    const ivec4* __restrict__ x4,
    const float2* __restrict__ table,
    fvec4* __restrict__ out4,
    int B4)
{
    const int i = blockIdx.x * 256 + threadIdx.x;
    if (i >= B4) return;
    ivec4 a = __builtin_nontemporal_load(x4 + 2 * i);
    ivec4 b = __builtin_nontemporal_load(x4 + 2 * i + 1);
    float2 t0 = table[(a.x - 1) * N_MAX + (a.y - 1)];
    float2 t1 = table[(a.z - 1) * N_MAX + (a.w - 1)];
    float2 t2 = table[(b.x - 1) * N_MAX + (b.y - 1)];
    float2 t3 = table[(b.z - 1) * N_MAX + (b.w - 1)];
    fvec4 o0v = {t0.x, t0.y, t1.x, t1.y};
    fvec4 o1v = {t2.x, t2.y, t3.x, t3.y};
    __builtin_nontemporal_store(o0v, out4 + 2 * i);
    __builtin_nontemporal_store(o1v, out4 + 2 * i + 1);
}

extern "C" void kernel_launch(void* const* d_in, const int* in_sizes, int n_in,
                              void* d_out, int out_size, void* d_ws, size_t ws_size,
                              hipStream_t stream) {
    const int*   x    = (const int*)d_in[0];
    const float* emb  = (const float*)d_in[1];
    const float* Wp   = (const float*)d_in[2];
    const float* bp   = (const float*)d_in[3];
    const float* Wn   = (const float*)d_in[4];
    const float* bn   = (const float*)d_in[5];
    const float* W1   = (const float*)d_in[6];
    const float* b1   = (const float*)d_in[7];
    const float* ln_g = (const float*)d_in[8];
    const float* ln_b = (const float*)d_in[9];
    const float* W2   = (const float*)d_in[10];
    const float* b2   = (const float*)d_in[11];
    const float* Wr   = (const float*)d_in[12];
    const float* br   = (const float*)d_in[13];

    const int B = in_sizes[0] / 2;

    float* wsf = (float*)d_ws;
    float2* table = (float2*)(wsf + TOF);

    chain_uv_kernel<<<2, 256, 0, stream>>>(
        emb, Wp, bp, Wn, bn, W1, b1, ln_g, ln_b, W2, b2, Wr, br, wsf);

    table_kernel<<<(TBL + 63) / 64, 64, 0, stream>>>(wsf, table);

    gather_kernel<<<(B / 4 + 255) / 256, 256, 0, stream>>>(
        (const ivec4*)x, table, (fvec4*)d_out, B / 4);
}